// Round 11
// baseline (121.882 us; speedup 1.0000x reference)
//
#include <hip/hip_runtime.h>
#include <math.h>

#define NCLUS 56
#define HH 224
#define WW 224
#define BB 32
#define CELLS (NCLUS * NCLUS) /* 3136 */
#define HW (HH * WW)

typedef float f32x4 __attribute__((ext_vector_type(4)));

// ---------------------------------------------------------------------------
// Kernel A: Sobel -> grad mag -> inverted -> 4x4 mean pool. (unchanged)
// ---------------------------------------------------------------------------
__global__ __launch_bounds__(256) void pool_kernel(const float* __restrict__ cf,
                                                   float* __restrict__ pooled) {
    __shared__ float lds[18][226];
    int b = blockIdx.x / 14;
    int grp = blockIdx.x - b * 14;
    int tid = threadIdx.x;
    const float* e = cf + ((size_t)b * 65 + 64) * HW;

    int y0 = grp * 16 - 1;
    for (int t = tid; t < 18 * 224; t += 256) {
        int r = t / 224;
        int c = t - r * 224;
        int y = y0 + r;
        lds[r][c + 1] = (y >= 0 && y < HH) ? e[y * WW + c] : 0.0f;
    }
    if (tid < 18) { lds[tid][0] = 0.0f; lds[tid][225] = 0.0f; }
    __syncthreads();

    if (tid >= 224) return;
    int lby = tid / 56;
    int bx = tid - lby * 56;
    int r0 = lby * 4;
    int c0 = bx * 4;

    float patch[6][6];
#pragma unroll
    for (int i = 0; i < 6; ++i)
#pragma unroll
        for (int j = 0; j < 6; ++j) patch[i][j] = lds[r0 + i][c0 + j];

    float s = 0.0f;
#pragma unroll
    for (int iy = 0; iy < 4; ++iy) {
#pragma unroll
        for (int ix = 0; ix < 4; ++ix) {
            float gx = (patch[iy][ix + 2] - patch[iy][ix])
                     + 2.0f * (patch[iy + 1][ix + 2] - patch[iy + 1][ix])
                     + (patch[iy + 2][ix + 2] - patch[iy + 2][ix]);
            float gy = (patch[iy + 2][ix] - patch[iy][ix])
                     + 2.0f * (patch[iy + 2][ix + 1] - patch[iy][ix + 1])
                     + (patch[iy + 2][ix + 2] - patch[iy][ix + 2]);
            float gm = sqrtf(gx * gx + gy * gy);
            s += 1.0f - 0.5f * gm;
        }
    }
    pooled[b * CELLS + (grp * 4 + lby) * NCLUS + bx] = s * 0.0625f;
}

// ---------------------------------------------------------------------------
// Kernel B: per-batch top-56 (radix select to <=128 + rank sort, exact jax
// order) + ALL exp tables: Fx[b][k][w], Fy[b][h][k], FyT[b][k][h].
// ---------------------------------------------------------------------------
__global__ __launch_bounds__(256) void topk_tables_kernel(
        const float* __restrict__ pooled, const float* __restrict__ stdp,
        float* __restrict__ Fx, float* __restrict__ Fy,
        float* __restrict__ FyT) {
    int b = blockIdx.x;
    int tid = threadIdx.x;
    __shared__ unsigned long long list[CELLS];
    __shared__ float sy_s[NCLUS], sx_s[NCLUS];
    __shared__ unsigned nlist_s;
    if (tid == 0) nlist_s = 0;

    if (tid < 64) {
        unsigned hi[49];
#pragma unroll
        for (int j = 0; j < 49; ++j) {
            int i = j * 64 + tid;
            unsigned u = __float_as_uint(pooled[b * CELLS + i]);
            hi[j] = (u & 0x80000000u) ? ~u : (u | 0x80000000u);
        }
        unsigned prefix = 0;
        unsigned cnt = CELLS;
        for (int bit = 31; bit >= 0; --bit) {
            if (cnt <= 128u) break;
            unsigned cand = prefix | (1u << bit);
            unsigned c = 0;
#pragma unroll
            for (int j = 0; j < 49; ++j) c += (hi[j] >= cand) ? 1u : 0u;
#pragma unroll
            for (int off = 32; off >= 1; off >>= 1)
                c += __shfl_xor(c, off, 64);
            if (c >= (unsigned)NCLUS) { prefix = cand; cnt = c; } // uniform
        }
#pragma unroll
        for (int j = 0; j < 49; ++j) {
            if (hi[j] >= prefix) {
                unsigned pos = atomicAdd(&nlist_s, 1u);
                unsigned i = (unsigned)(j * 64 + tid);
                list[pos] = ((unsigned long long)hi[j] << 32) |
                            (unsigned long long)(0xFFFFFFFFu - i);
            }
        }
    }
    __syncthreads();

    int N = (int)nlist_s;
    for (int c = tid; c < N; c += 256) {
        unsigned long long key = list[c];
        int r = 0;
        for (int j = 0; j < N; ++j) r += (list[j] > key) ? 1 : 0;
        if (r < NCLUS) {
            unsigned idx = 0xFFFFFFFFu - (unsigned)(key & 0xFFFFFFFFull);
            sy_s[r] = (float)(idx / NCLUS) / (float)NCLUS;
            sx_s[r] = (float)(idx % NCLUS) / (float)NCLUS;
        }
    }
    __syncthreads();

    float inv_std = 1.0f / stdp[0];
    // Fx[b][k][w] (w contiguous)
    for (int t = tid; t < NCLUS * WW; t += 256) {
        int k = t / WW;
        int w = t - k * WW;
        float tx = ((float)w / 224.0f - sx_s[k]) * inv_std;
        Fx[(size_t)b * NCLUS * WW + t] = expf(0.5f * expf(-(tx * tx)));
    }
    // Fy[b][h][k] (k contiguous)
    for (int t = tid; t < HH * NCLUS; t += 256) {
        int h = t / NCLUS;
        int k = t - h * NCLUS;
        float ty = ((float)h / 224.0f - sy_s[k]) * inv_std;
        Fy[(size_t)b * HH * NCLUS + t] = expf(0.5f * expf(-(ty * ty)));
    }
    // FyT[b][k][h] (h contiguous)
    for (int t = tid; t < NCLUS * HH; t += 256) {
        int k = t / HH;
        int h = t - k * HH;
        float ty = ((float)h / 224.0f - sy_s[k]) * inv_std;
        FyT[(size_t)b * NCLUS * HH + t] = expf(0.5f * expf(-(ty * ty)));
    }
}

// ---------------------------------------------------------------------------
// Kernel C1: softmax denominators, XCD-AFFINE. blockIdx = (b%8) + 8*((b/8)*28
// + band) so batch b's blocks run on XCD b%8 (round-robin dispatch). Sinv
// written with PLAIN stores -> stays dirty in that XCD's L2 (800KB/XCD).
// ---------------------------------------------------------------------------
__global__ __launch_bounds__(448) void sums_kernel(
        const float* __restrict__ Fx, const float* __restrict__ Fy,
        float* __restrict__ Sinv) {
    __shared__ float fx_lds[NCLUS][WW]; // 50,176 B
    __shared__ float fy_s[8 * NCLUS];   //  1,792 B
    int xcd = blockIdx.x & 7;
    int r = blockIdx.x >> 3;
    int bq = r / 28;
    int band = r - bq * 28;
    int b = bq * 8 + xcd;
    int h0 = band * 8;
    int tid = threadIdx.x;

    const f32x4* fxg = (const f32x4*)(Fx + (size_t)b * NCLUS * WW);
    f32x4* fxl = (f32x4*)&fx_lds[0][0];
    for (int t = tid; t < NCLUS * WW / 4; t += 448) fxl[t] = fxg[t];
    fy_s[tid] = Fy[((size_t)b * HH + h0) * NCLUS + tid];
    __syncthreads();

    int row = tid / 56;      // 0..7
    int wq = tid - row * 56; // 0..55
    const float* fyp = fy_s + row * NCLUS;

    float s0 = 0.f, s1 = 0.f, s2 = 0.f, s3 = 0.f;
#pragma unroll 8
    for (int k = 0; k < NCLUS; ++k) {
        float fy = fyp[k];
        f32x4 fx = *(const f32x4*)&fx_lds[k][wq * 4];
        s0 = fmaf(fy, fx.x, s0);
        s1 = fmaf(fy, fx.y, s1);
        s2 = fmaf(fy, fx.z, s2);
        s3 = fmaf(fy, fx.w, s3);
    }
    f32x4 rv;
    rv.x = 1.0f / s0;
    rv.y = 1.0f / s1;
    rv.z = 1.0f / s2;
    rv.w = 1.0f / s3;
    // plain store: keep resident in this XCD's L2 for scale_kernel
    *(f32x4*)(Sinv + (size_t)b * HW + (size_t)(h0 + row) * WW + wq * 4) = rv;
}

// ---------------------------------------------------------------------------
// Kernel C2: scale + store. One block per (b,k) plane, XCD-AFFINE (same
// b%8 mapping -> Sinv[b] reads hit the local L2; per-XCD working set
// 4 batches x 200KB = 800KB << 4MB, vs R6's thrashing 6.4MB). Writes one
// contiguous 200KB plane per block via NT stores (fill-kernel-shaped
// stream, 7 blocks/CU exact, all 1792 blocks co-resident).
// ---------------------------------------------------------------------------
__global__ __launch_bounds__(256) void scale_kernel(
        const float* __restrict__ Fx, const float* __restrict__ FyT,
        const float* __restrict__ Sinv, float* __restrict__ out) {
    __shared__ float fx_l[WW];
    __shared__ float fy_l[HH];
    int xcd = blockIdx.x & 7;
    int r = blockIdx.x >> 3;
    int bq = r / 56;
    int k = r - bq * 56;
    int b = bq * 8 + xcd;
    int tid = threadIdx.x;

    if (tid < 224) {
        fx_l[tid] = Fx[((size_t)b * NCLUS + k) * WW + tid];
        fy_l[tid] = FyT[((size_t)b * NCLUS + k) * HH + tid];
    }
    __syncthreads();

    const f32x4* sp = (const f32x4*)(Sinv + (size_t)b * HW);
    f32x4* op = (f32x4*)(out + ((size_t)b * NCLUS + k) * HW);
#pragma unroll 7
    for (int i = 0; i < 49; ++i) {
        int e = i * 256 + tid;   // quad index within plane, 0..12543
        int h = e / 56;
        int w4 = e - h * 56;
        f32x4 sv = sp[e];
        float fy = fy_l[h];
        f32x4 fx = *(const f32x4*)&fx_l[w4 * 4];
        f32x4 o;
        o.x = (fy * fx.x) * sv.x;
        o.y = (fy * fx.y) * sv.y;
        o.z = (fy * fx.z) * sv.z;
        o.w = (fy * fx.w) * sv.w;
        __builtin_nontemporal_store(o, op + e);
    }
}

// ---------------------------------------------------------------------------
extern "C" void kernel_launch(void* const* d_in, const int* in_sizes, int n_in,
                              void* d_out, int out_size, void* d_ws,
                              size_t ws_size, hipStream_t stream) {
    const float* cf = (const float*)d_in[0];   // (32, 65, 224, 224) f32
    const float* stdp = (const float*)d_in[1]; // scalar f32
    float* out = (float*)d_out;                // (32, 56, 224, 224) f32

    char* ws = (char*)d_ws;
    // pooled (400KB) aliases the start of Sinv: pooled is dead after
    // topk_tables runs; sums (later) overwrites the region. Deterministic
    // across graph replays (pool rewrites pooled first each call).
    float* pooled = (float*)ws;                          // 401 KB (alias)
    float* Sinv   = (float*)ws;                          // 6.42 MB
    float* Fx  = (float*)(ws + 7 * 1024 * 1024);         // 1.61 MB
    float* Fy  = (float*)(ws + 9 * 1024 * 1024);         // 1.61 MB
    float* FyT = (float*)(ws + 11 * 1024 * 1024);        // 1.61 MB

    pool_kernel<<<BB * 14, 256, 0, stream>>>(cf, pooled);
    topk_tables_kernel<<<BB, 256, 0, stream>>>(pooled, stdp, Fx, Fy, FyT);
    sums_kernel<<<BB * 28, 448, 0, stream>>>(Fx, Fy, Sinv);
    scale_kernel<<<BB * NCLUS, 256, 0, stream>>>(Fx, FyT, Sinv, out);
}

// Round 12
// 118.151 us; speedup vs baseline: 1.0316x; 1.0316x over previous
//
#include <hip/hip_runtime.h>
#include <math.h>

#define NCLUS 56
#define HH 224
#define WW 224
#define BB 32
#define CELLS (NCLUS * NCLUS) /* 3136 */
#define HW (HH * WW)
#define KSPL 28  /* k-planes per scale block (56/2) */

typedef float f32x4 __attribute__((ext_vector_type(4)));

// ---------------------------------------------------------------------------
// Kernel A: Sobel -> grad mag -> inverted -> 4x4 mean pool. (unchanged)
// ---------------------------------------------------------------------------
__global__ __launch_bounds__(256) void pool_kernel(const float* __restrict__ cf,
                                                   float* __restrict__ pooled) {
    __shared__ float lds[18][226];
    int b = blockIdx.x / 14;
    int grp = blockIdx.x - b * 14;
    int tid = threadIdx.x;
    const float* e = cf + ((size_t)b * 65 + 64) * HW;

    int y0 = grp * 16 - 1;
    for (int t = tid; t < 18 * 224; t += 256) {
        int r = t / 224;
        int c = t - r * 224;
        int y = y0 + r;
        lds[r][c + 1] = (y >= 0 && y < HH) ? e[y * WW + c] : 0.0f;
    }
    if (tid < 18) { lds[tid][0] = 0.0f; lds[tid][225] = 0.0f; }
    __syncthreads();

    if (tid >= 224) return;
    int lby = tid / 56;
    int bx = tid - lby * 56;
    int r0 = lby * 4;
    int c0 = bx * 4;

    float patch[6][6];
#pragma unroll
    for (int i = 0; i < 6; ++i)
#pragma unroll
        for (int j = 0; j < 6; ++j) patch[i][j] = lds[r0 + i][c0 + j];

    float s = 0.0f;
#pragma unroll
    for (int iy = 0; iy < 4; ++iy) {
#pragma unroll
        for (int ix = 0; ix < 4; ++ix) {
            float gx = (patch[iy][ix + 2] - patch[iy][ix])
                     + 2.0f * (patch[iy + 1][ix + 2] - patch[iy + 1][ix])
                     + (patch[iy + 2][ix + 2] - patch[iy + 2][ix]);
            float gy = (patch[iy + 2][ix] - patch[iy][ix])
                     + 2.0f * (patch[iy + 2][ix + 1] - patch[iy][ix + 1])
                     + (patch[iy + 2][ix + 2] - patch[iy][ix + 2]);
            float gm = sqrtf(gx * gx + gy * gy);
            s += 1.0f - 0.5f * gm;
        }
    }
    pooled[b * CELLS + (grp * 4 + lby) * NCLUS + bx] = s * 0.0625f;
}

// ---------------------------------------------------------------------------
// Kernel B: per-batch top-56 (radix select to <=128 + rank sort, exact jax
// order) + exp tables Fx[b][k][w], Fy[b][h][k].
// ---------------------------------------------------------------------------
__global__ __launch_bounds__(256) void topk_tables_kernel(
        const float* __restrict__ pooled, const float* __restrict__ stdp,
        float* __restrict__ Fx, float* __restrict__ Fy) {
    int b = blockIdx.x;
    int tid = threadIdx.x;
    __shared__ unsigned long long list[CELLS];
    __shared__ float sy_s[NCLUS], sx_s[NCLUS];
    __shared__ unsigned nlist_s;
    if (tid == 0) nlist_s = 0;

    if (tid < 64) {
        unsigned hi[49];
#pragma unroll
        for (int j = 0; j < 49; ++j) {
            int i = j * 64 + tid;
            unsigned u = __float_as_uint(pooled[b * CELLS + i]);
            hi[j] = (u & 0x80000000u) ? ~u : (u | 0x80000000u);
        }
        unsigned prefix = 0;
        unsigned cnt = CELLS;
        for (int bit = 31; bit >= 0; --bit) {
            if (cnt <= 128u) break;
            unsigned cand = prefix | (1u << bit);
            unsigned c = 0;
#pragma unroll
            for (int j = 0; j < 49; ++j) c += (hi[j] >= cand) ? 1u : 0u;
#pragma unroll
            for (int off = 32; off >= 1; off >>= 1)
                c += __shfl_xor(c, off, 64);
            if (c >= (unsigned)NCLUS) { prefix = cand; cnt = c; } // uniform
        }
#pragma unroll
        for (int j = 0; j < 49; ++j) {
            if (hi[j] >= prefix) {
                unsigned pos = atomicAdd(&nlist_s, 1u);
                unsigned i = (unsigned)(j * 64 + tid);
                list[pos] = ((unsigned long long)hi[j] << 32) |
                            (unsigned long long)(0xFFFFFFFFu - i);
            }
        }
    }
    __syncthreads();

    int N = (int)nlist_s;
    for (int c = tid; c < N; c += 256) {
        unsigned long long key = list[c];
        int r = 0;
        for (int j = 0; j < N; ++j) r += (list[j] > key) ? 1 : 0;
        if (r < NCLUS) {
            unsigned idx = 0xFFFFFFFFu - (unsigned)(key & 0xFFFFFFFFull);
            sy_s[r] = (float)(idx / NCLUS) / (float)NCLUS;
            sx_s[r] = (float)(idx % NCLUS) / (float)NCLUS;
        }
    }
    __syncthreads();

    float inv_std = 1.0f / stdp[0];
    // Fx[b][k][w] (w contiguous) -- same formula/ops as R4's in-kernel gen.
    for (int t = tid; t < NCLUS * WW; t += 256) {
        int k = t / WW;
        int w = t - k * WW;
        float tx = ((float)w / 224.0f - sx_s[k]) * inv_std;
        Fx[(size_t)b * NCLUS * WW + t] = expf(0.5f * expf(-(tx * tx)));
    }
    // Fy[b][h][k] (k contiguous)
    for (int t = tid; t < HH * NCLUS; t += 256) {
        int h = t / NCLUS;
        int k = t - h * NCLUS;
        float ty = ((float)h / 224.0f - sy_s[k]) * inv_std;
        Fy[(size_t)b * HH * NCLUS + t] = expf(0.5f * expf(-(ty * ty)));
    }
}

// ---------------------------------------------------------------------------
// Kernel C1: softmax denominators -> Sinv (6.4MB). R4 geometry (896 blocks,
// 448 thr, full 50KB fx LDS) but stages tables from global (no exp work).
// Writes are tiny; this kernel's phase structure doesn't matter.
// ---------------------------------------------------------------------------
__global__ __launch_bounds__(448) void sums_kernel(
        const float* __restrict__ Fx, const float* __restrict__ Fy,
        float* __restrict__ Sinv) {
    __shared__ float fx_lds[NCLUS][WW]; // 50,176 B
    __shared__ float fy_s[8 * NCLUS];   //  1,792 B
    int blk = blockIdx.x;
    int b = blk / 28;
    int h0 = (blk - b * 28) * 8;
    int tid = threadIdx.x;

    const f32x4* fxg = (const f32x4*)(Fx + (size_t)b * NCLUS * WW);
    f32x4* fxl = (f32x4*)&fx_lds[0][0];
#pragma unroll
    for (int t = 0; t < 7; ++t) fxl[t * 448 + tid] = fxg[t * 448 + tid];
    fy_s[tid] = Fy[((size_t)b * HH + h0) * NCLUS + tid];
    __syncthreads();

    int row = tid / 56;      // 0..7
    int wq = tid - row * 56; // 0..55
    const float* fyp = fy_s + row * NCLUS;

    float s0 = 0.f, s1 = 0.f, s2 = 0.f, s3 = 0.f;
#pragma unroll 8
    for (int k = 0; k < NCLUS; ++k) {
        float fy = fyp[k];
        f32x4 fx = *(const f32x4*)&fx_lds[k][wq * 4];
        s0 = fmaf(fy, fx.x, s0);
        s1 = fmaf(fy, fx.y, s1);
        s2 = fmaf(fy, fx.z, s2);
        s3 = fmaf(fy, fx.w, s3);
    }
    f32x4 rv;
    rv.x = 1.0f / s0;
    rv.y = 1.0f / s1;
    rv.z = 1.0f / s2;
    rv.w = 1.0f / s3;
    *(f32x4*)(Sinv + (size_t)b * HW + (size_t)(h0 + row) * WW + wq * 4) = rv;
}

// ---------------------------------------------------------------------------
// Kernel C2: SINGLE-PHASE store stream (the phase-duty fix). Block = (b,
// 8-row band, k-half): stages 28-plane fx half (25KB LDS -> 4 blocks/CU,
// 28 waves/CU) + 8x28 fy + reads its Sinv quad ONCE (12.8MB total logical,
// vs R6's thrashing 359MB). Then 28 iterations of pure
// ds_read -> 4 mul -> NT store: stores flow continuously from ~1us on,
// no exp prologue, no storeless sum phase.
// ---------------------------------------------------------------------------
__global__ __launch_bounds__(448) void scale_kernel(
        const float* __restrict__ Fx, const float* __restrict__ Fy,
        const float* __restrict__ Sinv, float* __restrict__ out) {
    __shared__ float fx_lds[KSPL][WW];   // 25,088 B
    __shared__ float fy_s[8 * KSPL];     //    896 B
    int blk = blockIdx.x;
    int b = blk / 56;
    int r = blk - b * 56;
    int band = r >> 1;
    int half = r & 1;
    int h0 = band * 8;
    int k0 = half * KSPL;
    int tid = threadIdx.x;

    int row = tid / 56;      // 0..7
    int wq = tid - row * 56; // 0..55

    // issue the Sinv read early; latency hides under staging + barrier
    f32x4 sv = *(const f32x4*)(Sinv + (size_t)b * HW +
                               (size_t)(h0 + row) * WW + wq * 4);

    // stage fx half: 28*224 floats = 6272 = 448 threads x 14 (float4 x 3.5)
    const f32x4* fxg = (const f32x4*)(Fx + ((size_t)b * NCLUS + k0) * WW);
    f32x4* fxl = (f32x4*)&fx_lds[0][0];
#pragma unroll
    for (int t = 0; t < 3; ++t) fxl[t * 448 + tid] = fxg[t * 448 + tid];
    if (tid < 224) fxl[3 * 448 + tid] = fxg[3 * 448 + tid];
    // stage fy: 8 rows x 28 k
    if (tid < 8 * KSPL) {
        int rr = tid / KSPL;
        int kk = tid - rr * KSPL;
        fy_s[tid] = Fy[((size_t)b * HH + h0 + rr) * NCLUS + k0 + kk];
    }
    __syncthreads();

    const float* fyp = fy_s + row * KSPL;
    float* op = out + ((size_t)b * NCLUS + k0) * HW +
                (size_t)(h0 + row) * WW + wq * 4;
#pragma unroll 7
    for (int kk = 0; kk < KSPL; ++kk) {
        float fy = fyp[kk];
        f32x4 fx = *(const f32x4*)&fx_lds[kk][wq * 4];
        f32x4 o;
        o.x = (fy * fx.x) * sv.x;
        o.y = (fy * fx.y) * sv.y;
        o.z = (fy * fx.z) * sv.z;
        o.w = (fy * fx.w) * sv.w;
        __builtin_nontemporal_store(o, (f32x4*)op);
        op += HW;
    }
}

// ---------------------------------------------------------------------------
extern "C" void kernel_launch(void* const* d_in, const int* in_sizes, int n_in,
                              void* d_out, int out_size, void* d_ws,
                              size_t ws_size, hipStream_t stream) {
    const float* cf = (const float*)d_in[0];   // (32, 65, 224, 224) f32
    const float* stdp = (const float*)d_in[1]; // scalar f32
    float* out = (float*)d_out;                // (32, 56, 224, 224) f32

    char* ws = (char*)d_ws;
    float* pooled = (float*)ws;                      // 401 KB
    float* Sinv = (float*)(ws + 1 * 1024 * 1024);    // 6.42 MB
    float* Fx = (float*)(ws + 8 * 1024 * 1024);      // 1.61 MB
    float* Fy = (float*)(ws + 10 * 1024 * 1024);     // 1.61 MB

    pool_kernel<<<BB * 14, 256, 0, stream>>>(cf, pooled);
    topk_tables_kernel<<<BB, 256, 0, stream>>>(pooled, stdp, Fx, Fy);
    sums_kernel<<<BB * 28, 448, 0, stream>>>(Fx, Fy, Sinv);
    scale_kernel<<<BB * NCLUS, 448, 0, stream>>>(Fx, Fy, Sinv, out);
}